// Round 3
// baseline (454.965 us; speedup 1.0000x reference)
//
#include <hip/hip_runtime.h>
#include <math.h>

// ---------------- GEMM: C[M,N] = A[M,K] @ B[K,N] + bias[N] ----------------
// fp32 vector-ALU GEMM. BM=BN=64, BK=16, 256 threads, 4x4 per thread.
constexpr int BM = 64, BN = 64, BKd = 16;

__global__ __launch_bounds__(256) void gemm_bias(
    const float* __restrict__ A, const float* __restrict__ B,
    const float* __restrict__ bias, float* __restrict__ C,
    int M, int N, int K) {
  __shared__ __align__(16) float As[BKd][BM + 4];
  __shared__ __align__(16) float Bs[BKd][BN];
  const int bm = blockIdx.x * BM;
  const int bn = blockIdx.y * BN;
  const int tid = threadIdx.x;
  const int tr = (tid >> 4) << 2;     // output row within tile (0..60)
  const int tc = (tid & 15) << 2;     // output col within tile
  const int arow = tid >> 2;          // 0..63
  const int ak   = (tid & 3) << 2;    // 0,4,8,12
  const int bkr  = tid >> 4;          // 0..15
  const int bnc  = (tid & 15) << 2;   // 0..60

  float acc[4][4] = {};

  for (int k0 = 0; k0 < K; k0 += BKd) {
    const int gr = bm + arow;
    float4 av = make_float4(0.f, 0.f, 0.f, 0.f);
    if (gr < M) av = *(const float4*)&A[(size_t)gr * K + k0 + ak];
    As[ak + 0][arow] = av.x;
    As[ak + 1][arow] = av.y;
    As[ak + 2][arow] = av.z;
    As[ak + 3][arow] = av.w;
    *(float4*)&Bs[bkr][bnc] =
        *(const float4*)&B[(size_t)(k0 + bkr) * N + bn + bnc];
    __syncthreads();
#pragma unroll
    for (int kk = 0; kk < BKd; ++kk) {
      const float4 a4 = *(const float4*)&As[kk][tr];
      const float4 b4 = *(const float4*)&Bs[kk][tc];
      const float ar[4] = {a4.x, a4.y, a4.z, a4.w};
      const float br_[4] = {b4.x, b4.y, b4.z, b4.w};
#pragma unroll
      for (int i = 0; i < 4; ++i)
#pragma unroll
        for (int j = 0; j < 4; ++j)
          acc[i][j] = fmaf(ar[i], br_[j], acc[i][j]);
    }
    __syncthreads();
  }

#pragma unroll
  for (int i = 0; i < 4; ++i) {
    const int r = bm + tr + i;
    if (r < M) {
      float4 o;
      o.x = acc[i][0] + bias[bn + tc + 0];
      o.y = acc[i][1] + bias[bn + tc + 1];
      o.z = acc[i][2] + bias[bn + tc + 2];
      o.w = acc[i][3] + bias[bn + tc + 3];
      *(float4*)&C[(size_t)r * N + bn + tc] = o;
    }
  }
}

// ---------------- CSR build (bucket edges by dst) ----------------
__global__ void count_deg(const int* __restrict__ dst, int* __restrict__ deg,
                          int E) {
  int e = blockIdx.x * blockDim.x + threadIdx.x;
  if (e < E) atomicAdd(&deg[dst[e]], 1);
}

// single-block exclusive scan over 20000 degrees
__global__ __launch_bounds__(1024) void scan_offsets(
    const int* __restrict__ deg, int* __restrict__ off,
    int* __restrict__ cursor, int n) {
  __shared__ int sums[1024];
  const int tid = threadIdx.x;
  const int chunk = (n + 1023) / 1024;
  const int start = tid * chunk;
  const int end = min(start + chunk, n);
  int s = 0;
  for (int i = start; i < end; ++i) s += deg[i];
  sums[tid] = s;
  __syncthreads();
  for (int d = 1; d < 1024; d <<= 1) {
    int v = (tid >= d) ? sums[tid - d] : 0;
    __syncthreads();
    sums[tid] += v;
    __syncthreads();
  }
  int base = (tid == 0) ? 0 : sums[tid - 1];
  for (int i = start; i < end; ++i) {
    off[i] = base;
    cursor[i] = base;
    base += deg[i];
  }
  if (tid == 1023) off[n] = sums[1023];
}

__global__ void scatter_edges(const int* __restrict__ dst,
                              int* __restrict__ cursor, int* __restrict__ eid,
                              int E) {
  int e = blockIdx.x * blockDim.x + threadIdx.x;
  if (e < E) {
    int d = dst[e];
    int pos = atomicAdd(&cursor[d], 1);
    eid[pos] = e;
  }
}

// ---------------- Layer-1 aggregation ----------------
// D=128, H=4, C=32. One wave handles one (node, head-pair):
// lanes 0-31 = head 2p, lanes 32-63 = head 2p+1. Fused GATv2 score +
// online softmax + weighted accumulate + bias + relu. No atomics.
__global__ __launch_bounds__(256) void agg1(
    const float* __restrict__ xl, const float* __restrict__ xr,
    const float* __restrict__ att, const float* __restrict__ bias,
    const int* __restrict__ off, const int* __restrict__ eid,
    const int* __restrict__ srcA, float* __restrict__ h1, int n_nodes) {
  const int gw = (blockIdx.x * blockDim.x + threadIdx.x) >> 6;
  const int lane = threadIdx.x & 63;
  const int node = gw >> 1;
  if (node >= n_nodes) return;
  const int pair = gw & 1;
  const int h = pair * 2 + (lane >> 5);
  const int c = lane & 31;
  const int col = h * 32 + c;

  const float attv = att[col];            // att1[h][c]
  const float xrv = xr[node * 128 + col];
  const int s0 = off[node], s1 = off[node + 1];

  float m = -INFINITY, den = 0.f, acc = 0.f;
  for (int i = s0; i < s1; ++i) {
    const int e = eid[i];
    const int s = srcA[e];
    const float xlv = xl[s * 128 + col];
    float t = xlv + xrv;
    t = t >= 0.f ? t : 0.2f * t;
    float p = t * attv;
    // reduce within each 32-lane half (per-head dot product)
    p += __shfl_xor(p, 1);
    p += __shfl_xor(p, 2);
    p += __shfl_xor(p, 4);
    p += __shfl_xor(p, 8);
    p += __shfl_xor(p, 16);
    if (p > m) {
      const float sc = expf(m - p);   // m == -inf -> 0
      acc *= sc; den *= sc; m = p;
    }
    const float w = expf(p - m);
    den += w;
    acc += w * xlv;
  }
  const float res = (den > 0.f) ? acc / den : 0.f;
  const float o = res + bias[col];
  h1[node * 128 + col] = o > 0.f ? o : 0.f;
}

// ---------------- Layer-2 aggregation ----------------
// D=512, H=4, C=128. One wave per (node, head); each lane owns 2 channels.
// Writes h2 in place over xr2 (own row fully read first; no other block
// reads this row). Fused score + online softmax + accumulate + bias + relu.
__global__ __launch_bounds__(256) void agg2(
    const float* __restrict__ xl, const float* __restrict__ xr,
    const float* __restrict__ att, const float* __restrict__ bias,
    const int* __restrict__ off, const int* __restrict__ eid,
    const int* __restrict__ srcA, float* __restrict__ h2, int n_nodes) {
  const int gw = (blockIdx.x * blockDim.x + threadIdx.x) >> 6;
  const int lane = threadIdx.x & 63;
  const int node = gw >> 2;
  if (node >= n_nodes) return;
  const int h = gw & 3;
  const int col = h * 128 + lane * 2;

  const float2 attv = *(const float2*)&att[col];
  const float2 xrv = *(const float2*)&xr[(size_t)node * 512 + col];
  const int s0 = off[node], s1 = off[node + 1];

  float m = -INFINITY, den = 0.f;
  float accx = 0.f, accy = 0.f;
  for (int i = s0; i < s1; ++i) {
    const int e = eid[i];
    const int s = srcA[e];
    const float2 xlv = *(const float2*)&xl[(size_t)s * 512 + col];
    float t0 = xlv.x + xrv.x;
    t0 = t0 >= 0.f ? t0 : 0.2f * t0;
    float t1 = xlv.y + xrv.y;
    t1 = t1 >= 0.f ? t1 : 0.2f * t1;
    float p = t0 * attv.x + t1 * attv.y;
#pragma unroll
    for (int mask = 1; mask < 64; mask <<= 1) p += __shfl_xor(p, mask);
    if (p > m) {
      const float sc = expf(m - p);
      accx *= sc; accy *= sc; den *= sc; m = p;
    }
    const float w = expf(p - m);
    den += w;
    accx += w * xlv.x;
    accy += w * xlv.y;
  }
  const float inv = (den > 0.f) ? 1.f / den : 0.f;
  float o0 = accx * inv + bias[col];
  float o1 = accy * inv + bias[col + 1];
  o0 = o0 > 0.f ? o0 : 0.f;
  o1 = o1 > 0.f ? o1 : 0.f;
  float2 o = make_float2(o0, o1);
  *(float2*)&h2[(size_t)node * 512 + col] = o;
}

// ---------------- launch ----------------
extern "C" void kernel_launch(void* const* d_in, const int* in_sizes, int n_in,
                              void* d_out, int out_size, void* d_ws,
                              size_t ws_size, hipStream_t stream) {
  const float* x    = (const float*)d_in[0];
  const int*   ei   = (const int*)d_in[1];
  // d_in[2] edge_attr unused
  const float* Wl1  = (const float*)d_in[3];
  const float* bl1  = (const float*)d_in[4];
  const float* Wr1  = (const float*)d_in[5];
  const float* br1  = (const float*)d_in[6];
  const float* att1 = (const float*)d_in[7];
  const float* bias1= (const float*)d_in[8];
  const float* Wl2  = (const float*)d_in[9];
  const float* bl2  = (const float*)d_in[10];
  const float* Wr2  = (const float*)d_in[11];
  const float* br2  = (const float*)d_in[12];
  const float* att2 = (const float*)d_in[13];
  const float* bias2= (const float*)d_in[14];
  const float* Wlin = (const float*)d_in[15];
  const float* blin = (const float*)d_in[16];
  float* out = (float*)d_out;

  const int N = in_sizes[0] / 128;  // 20000
  const int E = in_sizes[1] / 2;    // 160000
  const int* srcA = ei;
  const int* dstA = ei + E;

  // workspace layout (with aliasing): ~93 MB
  float* R0 = (float*)d_ws;                 // xl1 (N*128) then xl2 (N*512)
  float* R1 = R0 + (size_t)N * 512;         // xr1 (N*128) then xr2 -> h2
  float* h1 = R1 + (size_t)N * 512;         // N*128
  int* deg    = (int*)(h1 + (size_t)N * 128);
  int* off    = deg + N;
  int* cursor = off + N + 1;
  int* eid    = cursor + N;

  float* xl1 = R0;
  float* xr1 = R1;
  float* xl2 = R0;
  float* xr2 = R1;
  float* h2  = R1;

  // CSR build by dst
  hipMemsetAsync(deg, 0, (size_t)N * sizeof(int), stream);
  count_deg<<<dim3((E + 255) / 256), dim3(256), 0, stream>>>(dstA, deg, E);
  scan_offsets<<<dim3(1), dim3(1024), 0, stream>>>(deg, off, cursor, N);
  scatter_edges<<<dim3((E + 255) / 256), dim3(256), 0, stream>>>(dstA, cursor,
                                                                 eid, E);

  const int gm = (N + BM - 1) / BM;  // 313
  // layer 1: xl1 = x@Wl1+bl1, xr1 = x@Wr1+br1   [20000,128]
  gemm_bias<<<dim3(gm, 128 / BN), dim3(256), 0, stream>>>(x, Wl1, bl1, xl1, N,
                                                          128, 128);
  gemm_bias<<<dim3(gm, 128 / BN), dim3(256), 0, stream>>>(x, Wr1, br1, xr1, N,
                                                          128, 128);
  // layer 1 aggregation -> h1 (relu fused)
  agg1<<<dim3(2 * N / 4), dim3(256), 0, stream>>>(xl1, xr1, att1, bias1, off,
                                                  eid, srcA, h1, N);
  // layer 2: xl2 = h1@Wl2+bl2, xr2 = h1@Wr2+br2   [20000,512]
  gemm_bias<<<dim3(gm, 512 / BN), dim3(256), 0, stream>>>(h1, Wl2, bl2, xl2, N,
                                                          512, 128);
  gemm_bias<<<dim3(gm, 512 / BN), dim3(256), 0, stream>>>(h1, Wr2, br2, xr2, N,
                                                          512, 128);
  // layer 2 aggregation -> h2 (in place over xr2, relu fused)
  agg2<<<dim3(4 * N / 4), dim3(256), 0, stream>>>(xl2, xr2, att2, bias2, off,
                                                  eid, srcA, h2, N);
  // output linear: out = h2@Wlin + blin   [20000,64]
  gemm_bias<<<dim3(gm, 64 / BN), dim3(256), 0, stream>>>(h2, Wlin, blin, out,
                                                         N, 64, 512);
}

// Round 4
// 344.956 us; speedup vs baseline: 1.3189x; 1.3189x over previous
//
#include <hip/hip_runtime.h>
#include <hip/hip_bf16.h>
#include <math.h>

typedef __attribute__((ext_vector_type(8))) short short8;
typedef __attribute__((ext_vector_type(8))) unsigned short ushort8;
typedef __attribute__((ext_vector_type(2))) unsigned short ushort2v;
typedef __attribute__((ext_vector_type(4))) float f32x4;

__device__ inline unsigned short f2bf(float v) {
  __hip_bfloat16 b = __float2bfloat16(v);
  return *reinterpret_cast<unsigned short*>(&b);
}
__device__ inline float bf2f(unsigned short u) {
  __hip_bfloat16 b = *reinterpret_cast<__hip_bfloat16*>(&u);
  return __bfloat162float(b);
}

// ============ split-bf16 MFMA GEMM over 3 K-segments ============
// C[M,N] = A[M,K]B[K,N] + bias, where A is stored as bf16 [M][2K] = [hi|lo]
// (row stride lda) and B is stored TRANSPOSED bf16 [N][2K] = [hi|lo]
// (row stride ldb). Computes AhiBhi + AloBhi + AhiBlo (fp32 accum) ==
// fp32-grade precision. Tiles: BM=128,BN=64,BK=64; 256 thr = 4 waves (2x2),
// each wave 64x32 via 16x16x32 bf16 MFMA.
__global__ __launch_bounds__(256) void gemm_split_mfma(
    const unsigned short* __restrict__ A, int lda,
    const unsigned short* __restrict__ B, int ldb,
    const float* __restrict__ bias, float* __restrict__ C,
    int M, int N, int K) {
  __shared__ unsigned short Asl[128][72];  // +8 pad: 144B row stride, 2-way max
  __shared__ unsigned short Bsl[64][72];
  const int bm = blockIdx.x * 128, bn = blockIdx.y * 64;
  const int tid = threadIdx.x;
  const int lane = tid & 63, wave = tid >> 6;
  const int wm = (wave >> 1) * 64, wn = (wave & 1) * 32;
  const int fr = lane & 15, kg = lane >> 4;
  f32x4 acc[4][2] = {};

  const int ar = tid >> 1, ac = (tid & 1) * 32;   // A staging: 128 rows x 64
  const int br = tid & 63, bc = (tid >> 6) * 16;  // B staging: 64 rows x 64
  const int agr = bm + ar;
  const unsigned short* Abase = A + (size_t)agr * lda;
  const unsigned short* Bbase = B + (size_t)(bn + br) * ldb;

  for (int seg = 0; seg < 3; ++seg) {
    const int aoff = (seg == 1) ? K : 0;  // A blocks: hi, lo, hi
    const int boff = (seg == 2) ? K : 0;  // B blocks: hi, hi, lo
    for (int k0 = 0; k0 < K; k0 += 64) {
      ushort8 a0 = {}, a1 = {}, a2 = {}, a3 = {};
      if (agr < M) {
        const ushort8* ap = (const ushort8*)(Abase + aoff + k0 + ac);
        a0 = ap[0]; a1 = ap[1]; a2 = ap[2]; a3 = ap[3];
      }
      const ushort8* bp = (const ushort8*)(Bbase + boff + k0 + bc);
      const ushort8 b0 = bp[0], b1 = bp[1];
      __syncthreads();  // previous tile's LDS reads complete
      {
        ushort8* as = (ushort8*)&Asl[ar][ac];
        as[0] = a0; as[1] = a1; as[2] = a2; as[3] = a3;
        ushort8* bs = (ushort8*)&Bsl[br][bc];
        bs[0] = b0; bs[1] = b1;
      }
      __syncthreads();
#pragma unroll
      for (int ks = 0; ks < 2; ++ks) {
        short8 av[4], bv[2];
#pragma unroll
        for (int mf = 0; mf < 4; ++mf)
          av[mf] = *(const short8*)&Asl[wm + mf * 16 + fr][ks * 32 + kg * 8];
#pragma unroll
        for (int nf = 0; nf < 2; ++nf)
          bv[nf] = *(const short8*)&Bsl[wn + nf * 16 + fr][ks * 32 + kg * 8];
#pragma unroll
        for (int mf = 0; mf < 4; ++mf)
#pragma unroll
          for (int nf = 0; nf < 2; ++nf)
            acc[mf][nf] = __builtin_amdgcn_mfma_f32_16x16x32_bf16(
                av[mf], bv[nf], acc[mf][nf], 0, 0, 0);
      }
    }
  }
  // C/D layout (m89-verified): col = lane&15, row = (lane>>4)*4 + reg
#pragma unroll
  for (int mf = 0; mf < 4; ++mf)
#pragma unroll
    for (int nf = 0; nf < 2; ++nf) {
      const int col = bn + wn + nf * 16 + fr;
      const float bv = bias[col];
#pragma unroll
      for (int r = 0; r < 4; ++r) {
        const int row = bm + wm + mf * 16 + kg * 4 + r;
        if (row < M) C[(size_t)row * N + col] = acc[mf][nf][r] + bv;
      }
    }
}

// ============ casts ============
// x [M][128] fp32 -> [M][256] bf16 (hi|lo)
__global__ void split_x_k(const float* __restrict__ X,
                          unsigned short* __restrict__ out, int total) {
  int i = blockIdx.x * 256 + threadIdx.x;
  if (i >= total) return;
  int row = i >> 7, c = i & 127;
  float v = X[i];
  unsigned short h = f2bf(v);
  out[(size_t)row * 256 + c] = h;
  out[(size_t)row * 256 + 128 + c] = f2bf(v - bf2f(h));
}

// W [K][N] fp32 -> Wt [N][2K] bf16 (hi|lo), transposed
__global__ void wsplit_t_k(const float* __restrict__ W,
                           unsigned short* __restrict__ Wt, int K, int N) {
  int n = blockIdx.x * 256 + threadIdx.x;
  int k = blockIdx.y;
  if (n >= N) return;
  float v = W[(size_t)k * N + n];
  unsigned short h = f2bf(v);
  Wt[(size_t)n * 2 * K + k] = h;
  Wt[(size_t)n * 2 * K + K + k] = f2bf(v - bf2f(h));
}

// ============ CSR build (bucket edges by dst, store src directly) ============
__global__ void count_deg(const int* __restrict__ dst, int* __restrict__ deg,
                          int E) {
  int e = blockIdx.x * blockDim.x + threadIdx.x;
  if (e < E) atomicAdd(&deg[dst[e]], 1);
}

__global__ __launch_bounds__(1024) void scan_offsets(
    const int* __restrict__ deg, int* __restrict__ off,
    int* __restrict__ cursor, int n) {
  __shared__ int sums[1024];
  const int tid = threadIdx.x;
  const int chunk = (n + 1023) / 1024;
  const int start = tid * chunk;
  const int end = min(start + chunk, n);
  int s = 0;
  for (int i = start; i < end; ++i) s += deg[i];
  sums[tid] = s;
  __syncthreads();
  for (int d = 1; d < 1024; d <<= 1) {
    int v = (tid >= d) ? sums[tid - d] : 0;
    __syncthreads();
    sums[tid] += v;
    __syncthreads();
  }
  int base = (tid == 0) ? 0 : sums[tid - 1];
  for (int i = start; i < end; ++i) {
    off[i] = base;
    cursor[i] = base;
    base += deg[i];
  }
  if (tid == 1023) off[n] = sums[1023];
}

__global__ void scatter_edges(const int* __restrict__ src,
                              const int* __restrict__ dst,
                              int* __restrict__ cursor, int* __restrict__ csrc,
                              int E) {
  int e = blockIdx.x * blockDim.x + threadIdx.x;
  if (e < E) {
    int pos = atomicAdd(&cursor[dst[e]], 1);
    csrc[pos] = src[e];  // store src id directly (no eid indirection)
  }
}

// ============ fused GATv2 aggregation: 1 wave per node, 4 heads ============
// 16-lane group g handles head g; lane owns CPL channels. Per edge: coalesced
// row gather, per-group 4-step shfl dot-reduce, branchless online softmax,
// 2-edge unroll for load-latency ILP. Output written as bf16 hi|lo [node][2D].
template <int CPL>
__global__ __launch_bounds__(256) void agg_fused(
    const float* __restrict__ xl, const float* __restrict__ xr,
    const float* __restrict__ att, const float* __restrict__ bias,
    const int* __restrict__ off, const int* __restrict__ csrc,
    unsigned short* __restrict__ outcat, int n_nodes) {
  constexpr int D = 64 * CPL;
  const int node = (int)((blockIdx.x * 256 + threadIdx.x) >> 6);
  if (node >= n_nodes) return;
  const int lane = threadIdx.x & 63;
  const int coff = (lane >> 4) * (16 * CPL) + (lane & 15) * CPL;

  float xrv[CPL], attv[CPL], acc[CPL];
  {
    const float* xp = xr + (size_t)node * D + coff;
    const float* ap = att + coff;
#pragma unroll
    for (int j = 0; j < CPL; ++j) {
      xrv[j] = xp[j];
      attv[j] = ap[j];
      acc[j] = 0.f;
    }
  }

  auto loadrow = [&](int s, float* r) {
    const float* p = xl + (size_t)s * D + coff;
    if constexpr (CPL == 8) {
      *(float4*)&r[0] = *(const float4*)p;
      *(float4*)&r[4] = *(const float4*)(p + 4);
    } else {
      *(float2*)&r[0] = *(const float2*)p;
    }
  };
  auto score = [&](const float* r) {
    float p = 0.f;
#pragma unroll
    for (int j = 0; j < CPL; ++j) {
      float t = r[j] + xrv[j];
      t = t >= 0.f ? t : 0.2f * t;
      p = fmaf(t, attv[j], p);
    }
    return p;
  };

  float m = -INFINITY, den = 0.f;
  int i = off[node];
  const int iend = off[node + 1];
  for (; i + 2 <= iend; i += 2) {
    const int s0 = csrc[i], s1 = csrc[i + 1];
    float r0[CPL], r1[CPL];
    loadrow(s0, r0);
    loadrow(s1, r1);
    float p0 = score(r0), p1 = score(r1);
#pragma unroll
    for (int msk = 1; msk < 16; msk <<= 1) {
      p0 += __shfl_xor(p0, msk);
      p1 += __shfl_xor(p1, msk);
    }
    const float nm = fmaxf(m, fmaxf(p0, p1));
    const float sc = __expf(m - nm);  // 0 when m == -inf
    const float w0 = __expf(p0 - nm);
    const float w1 = __expf(p1 - nm);
    den = den * sc + w0 + w1;
#pragma unroll
    for (int j = 0; j < CPL; ++j)
      acc[j] = fmaf(acc[j], sc, fmaf(w0, r0[j], w1 * r1[j]));
    m = nm;
  }
  if (i < iend) {
    const int s0 = csrc[i];
    float r0[CPL];
    loadrow(s0, r0);
    float p0 = score(r0);
#pragma unroll
    for (int msk = 1; msk < 16; msk <<= 1) p0 += __shfl_xor(p0, msk);
    const float nm = fmaxf(m, p0);
    const float sc = __expf(m - nm);
    const float w0 = __expf(p0 - nm);
    den = den * sc + w0;
#pragma unroll
    for (int j = 0; j < CPL; ++j) acc[j] = fmaf(acc[j], sc, w0 * r0[j]);
    m = nm;
  }

  const float inv = (den > 0.f) ? 1.f / den : 0.f;
  unsigned short hi[CPL], lo[CPL];
#pragma unroll
  for (int j = 0; j < CPL; ++j) {
    float o = fmaf(acc[j], inv, bias[coff + j]);
    o = o > 0.f ? o : 0.f;  // relu (layer output)
    hi[j] = f2bf(o);
    lo[j] = f2bf(o - bf2f(hi[j]));
  }
  unsigned short* po = outcat + (size_t)node * (2 * D) + coff;
  if constexpr (CPL == 8) {
    *(ushort8*)po = *(ushort8*)hi;
    *(ushort8*)(po + D) = *(ushort8*)lo;
  } else {
    *(ushort2v*)po = *(ushort2v*)hi;
    *(ushort2v*)(po + D) = *(ushort2v*)lo;
  }
}

// ============ launch ============
extern "C" void kernel_launch(void* const* d_in, const int* in_sizes, int n_in,
                              void* d_out, int out_size, void* d_ws,
                              size_t ws_size, hipStream_t stream) {
  const float* x    = (const float*)d_in[0];
  const int*   ei   = (const int*)d_in[1];
  const float* Wl1  = (const float*)d_in[3];
  const float* bl1  = (const float*)d_in[4];
  const float* Wr1  = (const float*)d_in[5];
  const float* br1  = (const float*)d_in[6];
  const float* att1 = (const float*)d_in[7];
  const float* bias1= (const float*)d_in[8];
  const float* Wl2  = (const float*)d_in[9];
  const float* bl2  = (const float*)d_in[10];
  const float* Wr2  = (const float*)d_in[11];
  const float* br2  = (const float*)d_in[12];
  const float* att2 = (const float*)d_in[13];
  const float* bias2= (const float*)d_in[14];
  const float* Wlin = (const float*)d_in[15];
  const float* blin = (const float*)d_in[16];
  float* out = (float*)d_out;

  const int N = in_sizes[0] / 128;  // 20000
  const int E = in_sizes[1] / 2;    // 160000
  const int* srcA = ei;
  const int* dstA = ei + E;

  // -------- workspace layout (~93.8 MB, matches proven footprint) --------
  char* base = (char*)d_ws;
  float* xl2 = (float*)base;                        // 40,960,000 B
  float* xr2 = (float*)(base + 40960000);           // 40,960,000 B (h2cat too)
  unsigned short* h1cat = (unsigned short*)(base + 81920000);  // 10,240,000 B
  unsigned short* wb = (unsigned short*)(base + 92160000);     // 786,432 B
  unsigned short* wl1t = wb;               // 128x256
  unsigned short* wr1t = wb + 32768;
  unsigned short* wl2t = wb + 65536;       // 512x256
  unsigned short* wr2t = wb + 196608;
  unsigned short* wlint = wb + 327680;     // 64x1024
  int* ib = (int*)(base + 92946432);
  int* deg = ib;
  int* off = ib + 20000;
  int* cursor = ib + 40001;
  int* csrc = ib + 60001;
  // aliases inside xl2 region (dead before xl2 is written):
  unsigned short* xcat = (unsigned short*)xl2;          // 10,240,000 B
  float* xl1 = (float*)(base + 10240000);               // 10,240,000 B
  float* xr1 = (float*)(base + 20480000);               // 10,240,000 B
  unsigned short* h2cat = (unsigned short*)xr2;         // in-place over xr2

  // -------- CSR build --------
  hipMemsetAsync(deg, 0, (size_t)N * sizeof(int), stream);
  count_deg<<<dim3((E + 255) / 256), dim3(256), 0, stream>>>(dstA, deg, E);
  scan_offsets<<<dim3(1), dim3(1024), 0, stream>>>(deg, off, cursor, N);
  scatter_edges<<<dim3((E + 255) / 256), dim3(256), 0, stream>>>(
      srcA, dstA, cursor, csrc, E);

  // -------- casts --------
  split_x_k<<<dim3((N * 128 + 255) / 256), dim3(256), 0, stream>>>(
      x, xcat, N * 128);
  wsplit_t_k<<<dim3(1, 128), dim3(256), 0, stream>>>(Wl1, wl1t, 128, 128);
  wsplit_t_k<<<dim3(1, 128), dim3(256), 0, stream>>>(Wr1, wr1t, 128, 128);
  wsplit_t_k<<<dim3(2, 128), dim3(256), 0, stream>>>(Wl2, wl2t, 128, 512);
  wsplit_t_k<<<dim3(2, 128), dim3(256), 0, stream>>>(Wr2, wr2t, 128, 512);
  wsplit_t_k<<<dim3(1, 512), dim3(256), 0, stream>>>(Wlin, wlint, 512, 64);

  const int gm = (N + 127) / 128;  // 157
  // -------- layer 1 --------
  gemm_split_mfma<<<dim3(gm, 2), dim3(256), 0, stream>>>(
      xcat, 256, wl1t, 256, bl1, xl1, N, 128, 128);
  gemm_split_mfma<<<dim3(gm, 2), dim3(256), 0, stream>>>(
      xcat, 256, wr1t, 256, br1, xr1, N, 128, 128);
  agg_fused<2><<<dim3((N + 3) / 4), dim3(256), 0, stream>>>(
      xl1, xr1, att1, bias1, off, csrc, h1cat, N);
  // -------- layer 2 --------
  gemm_split_mfma<<<dim3(gm, 8), dim3(256), 0, stream>>>(
      h1cat, 256, wl2t, 256, bl2, xl2, N, 512, 128);
  gemm_split_mfma<<<dim3(gm, 8), dim3(256), 0, stream>>>(
      h1cat, 256, wr2t, 256, br2, xr2, N, 512, 128);
  agg_fused<8><<<dim3((N + 3) / 4), dim3(256), 0, stream>>>(
      xl2, xr2, att2, bias2, off, csrc, h2cat, N);
  // -------- output linear --------
  gemm_split_mfma<<<dim3(gm, 1), dim3(256), 0, stream>>>(
      h2cat, 1024, wlint, 1024, blin, out, N, 64, 512);
}

// Round 5
// 319.102 us; speedup vs baseline: 1.4258x; 1.0810x over previous
//
#include <hip/hip_runtime.h>
#include <hip/hip_bf16.h>
#include <math.h>

typedef __attribute__((ext_vector_type(8))) short short8;
typedef __attribute__((ext_vector_type(8))) unsigned short ushort8;
typedef __attribute__((ext_vector_type(2))) unsigned short ushort2v;
typedef __attribute__((ext_vector_type(4))) float f32x4;

__device__ inline unsigned short f2bf(float v) {
  __hip_bfloat16 b = __float2bfloat16(v);
  return *reinterpret_cast<unsigned short*>(&b);
}
__device__ inline float bf2f(unsigned short u) {
  __hip_bfloat16 b = *reinterpret_cast<__hip_bfloat16*>(&u);
  return __bfloat162float(b);
}

// ============ split-bf16 MFMA GEMM over 3 K-segments ============
// C[M,N] = A[M,K]B[K,N] + bias. A stored bf16 [M][2K]=[hi|lo] (stride lda),
// B stored TRANSPOSED bf16 [N][2K]=[hi|lo] (stride ldb). Computes
// AhiBhi + AloBhi + AhiBlo in fp32 accum == fp32-grade precision.
// PAIR: two B/C operands share one A staging (xl/xr GEMMs fused).
// Software-pipelined: tile t+1's global loads issue before MFMA(t).
// Tiles: BM=128, BN=64, BK=64; 4 waves (2x2), 64x32 per wave per output.
template <bool PAIR>
__global__ __launch_bounds__(256) void gemm_split(
    const unsigned short* __restrict__ A, int lda,
    const unsigned short* __restrict__ B0,
    const unsigned short* __restrict__ B1, int ldb,
    const float* __restrict__ bias0, const float* __restrict__ bias1,
    float* __restrict__ C0, float* __restrict__ C1, int M, int N, int K) {
  constexpr int NB = PAIR ? 2 : 1;
  __shared__ unsigned short Asl[128][72];  // +8 pad: 144B row stride
  __shared__ unsigned short Bsl[NB][64][72];
  const int bm = blockIdx.x * 128, bn = blockIdx.y * 64;
  const int tid = threadIdx.x;
  const int lane = tid & 63, wave = tid >> 6;
  const int wm = (wave >> 1) * 64, wn = (wave & 1) * 32;
  const int fr = lane & 15, kg = lane >> 4;
  f32x4 acc0[4][2] = {};
  f32x4 acc1[4][2] = {};

  const int ar = tid >> 1, ac = (tid & 1) * 32;   // A staging: 128 x 64
  const int br = tid & 63, bc = (tid >> 6) * 16;  // B staging: 64 x 64
  const int agr = bm + ar;
  const unsigned short* Abase = A + (size_t)agr * lda;
  const unsigned short* B0base = B0 + (size_t)(bn + br) * ldb;
  const unsigned short* B1base = PAIR ? B1 + (size_t)(bn + br) * ldb : nullptr;

  const int KT = K >> 6;       // K-tiles per segment
  const int T = 3 * KT;        // total tiles (3 precision segments)

  ushort8 ra[4], rb0[2], rb1[2];
  auto load_t = [&](int t) {
    const int seg = t / KT;
    const int k0 = (t - seg * KT) << 6;
    const int ao = (seg == 1) ? K : 0;  // A: hi, lo, hi
    const int bo = (seg == 2) ? K : 0;  // B: hi, hi, lo
    ushort8 z = {};
    ra[0] = ra[1] = ra[2] = ra[3] = z;
    if (agr < M) {
      const ushort8* ap = (const ushort8*)(Abase + ao + k0 + ac);
      ra[0] = ap[0]; ra[1] = ap[1]; ra[2] = ap[2]; ra[3] = ap[3];
    }
    const ushort8* bp0 = (const ushort8*)(B0base + bo + k0 + bc);
    rb0[0] = bp0[0]; rb0[1] = bp0[1];
    if constexpr (PAIR) {
      const ushort8* bp1 = (const ushort8*)(B1base + bo + k0 + bc);
      rb1[0] = bp1[0]; rb1[1] = bp1[1];
    }
  };

  load_t(0);
  for (int t = 0; t < T; ++t) {
    __syncthreads();  // all waves done reading LDS tile t-1
    {
      ushort8* as = (ushort8*)&Asl[ar][ac];
      as[0] = ra[0]; as[1] = ra[1]; as[2] = ra[2]; as[3] = ra[3];
      ushort8* bs0 = (ushort8*)&Bsl[0][br][bc];
      bs0[0] = rb0[0]; bs0[1] = rb0[1];
      if constexpr (PAIR) {
        ushort8* bs1 = (ushort8*)&Bsl[1][br][bc];
        bs1[0] = rb1[0]; bs1[1] = rb1[1];
      }
    }
    __syncthreads();  // LDS tile t ready
    if (t + 1 < T) load_t(t + 1);  // overlap next loads with MFMA
#pragma unroll
    for (int ks = 0; ks < 2; ++ks) {
      short8 av[4], bv0[2], bv1[2];
#pragma unroll
      for (int mf = 0; mf < 4; ++mf)
        av[mf] = *(const short8*)&Asl[wm + mf * 16 + fr][ks * 32 + kg * 8];
#pragma unroll
      for (int nf = 0; nf < 2; ++nf) {
        bv0[nf] = *(const short8*)&Bsl[0][wn + nf * 16 + fr][ks * 32 + kg * 8];
        if constexpr (PAIR)
          bv1[nf] =
              *(const short8*)&Bsl[1][wn + nf * 16 + fr][ks * 32 + kg * 8];
      }
#pragma unroll
      for (int mf = 0; mf < 4; ++mf)
#pragma unroll
        for (int nf = 0; nf < 2; ++nf) {
          acc0[mf][nf] = __builtin_amdgcn_mfma_f32_16x16x32_bf16(
              av[mf], bv0[nf], acc0[mf][nf], 0, 0, 0);
          if constexpr (PAIR)
            acc1[mf][nf] = __builtin_amdgcn_mfma_f32_16x16x32_bf16(
                av[mf], bv1[nf], acc1[mf][nf], 0, 0, 0);
        }
    }
  }
  // C/D layout (m89-verified): col = lane&15, row = (lane>>4)*4 + reg
#pragma unroll
  for (int mf = 0; mf < 4; ++mf)
#pragma unroll
    for (int nf = 0; nf < 2; ++nf) {
      const int col = bn + wn + nf * 16 + fr;
      const float bv0 = bias0[col];
      const float bv1 = PAIR ? bias1[col] : 0.f;
#pragma unroll
      for (int r = 0; r < 4; ++r) {
        const int row = bm + wm + mf * 16 + kg * 4 + r;
        if (row < M) {
          C0[(size_t)row * N + col] = acc0[mf][nf][r] + bv0;
          if constexpr (PAIR)
            C1[(size_t)row * N + col] = acc1[mf][nf][r] + bv1;
        }
      }
    }
}

// ============ casts ============
__global__ void split_x_k(const float* __restrict__ X,
                          unsigned short* __restrict__ out, int total) {
  int i = blockIdx.x * 256 + threadIdx.x;
  if (i >= total) return;
  int row = i >> 7, c = i & 127;
  float v = X[i];
  unsigned short h = f2bf(v);
  out[(size_t)row * 256 + c] = h;
  out[(size_t)row * 256 + 128 + c] = f2bf(v - bf2f(h));
}

__global__ void wsplit_t_k(const float* __restrict__ W,
                           unsigned short* __restrict__ Wt, int K, int N) {
  int n = blockIdx.x * 256 + threadIdx.x;
  int k = blockIdx.y;
  if (n >= N) return;
  float v = W[(size_t)k * N + n];
  unsigned short h = f2bf(v);
  Wt[(size_t)n * 2 * K + k] = h;
  Wt[(size_t)n * 2 * K + K + k] = f2bf(v - bf2f(h));
}

// ============ CSR build ============
__global__ void count_deg(const int* __restrict__ dst, int* __restrict__ deg,
                          int E) {
  int e = blockIdx.x * blockDim.x + threadIdx.x;
  if (e < E) atomicAdd(&deg[dst[e]], 1);
}

__global__ __launch_bounds__(1024) void scan_offsets(
    const int* __restrict__ deg, int* __restrict__ off,
    int* __restrict__ cursor, int n) {
  __shared__ int sums[1024];
  const int tid = threadIdx.x;
  const int chunk = (n + 1023) / 1024;
  const int start = tid * chunk;
  const int end = min(start + chunk, n);
  int s = 0;
  for (int i = start; i < end; ++i) s += deg[i];
  sums[tid] = s;
  __syncthreads();
  for (int d = 1; d < 1024; d <<= 1) {
    int v = (tid >= d) ? sums[tid - d] : 0;
    __syncthreads();
    sums[tid] += v;
    __syncthreads();
  }
  int base = (tid == 0) ? 0 : sums[tid - 1];
  for (int i = start; i < end; ++i) {
    off[i] = base;
    cursor[i] = base;
    base += deg[i];
  }
  if (tid == 1023) off[n] = sums[1023];
}

__global__ void scatter_edges(const int* __restrict__ src,
                              const int* __restrict__ dst,
                              int* __restrict__ cursor, int* __restrict__ csrc,
                              int E) {
  int e = blockIdx.x * blockDim.x + threadIdx.x;
  if (e < E) {
    int pos = atomicAdd(&cursor[dst[e]], 1);
    csrc[pos] = src[e];
  }
}

// ============ fused GATv2 aggregation: 1 wave per node, 4 heads ============
// 16-lane group g = head g; lane owns CPL channels. 4-edge unroll: 4
// independent row gathers + score chains in flight; branchless 4-way
// online-softmax merge. Output bf16 hi|lo [node][2D].
template <int CPL>
__global__ __launch_bounds__(256) void agg_fused(
    const float* __restrict__ xl, const float* __restrict__ xr,
    const float* __restrict__ att, const float* __restrict__ bias,
    const int* __restrict__ off, const int* __restrict__ csrc,
    unsigned short* __restrict__ outcat, int n_nodes) {
  constexpr int D = 64 * CPL;
  const int node = (int)((blockIdx.x * 256 + threadIdx.x) >> 6);
  if (node >= n_nodes) return;
  const int lane = threadIdx.x & 63;
  const int coff = (lane >> 4) * (16 * CPL) + (lane & 15) * CPL;

  float xrv[CPL], attv[CPL], acc[CPL];
  {
    const float* xp = xr + (size_t)node * D + coff;
    const float* ap = att + coff;
#pragma unroll
    for (int j = 0; j < CPL; ++j) {
      xrv[j] = xp[j];
      attv[j] = ap[j];
      acc[j] = 0.f;
    }
  }

  auto loadrow = [&](int s, float* r) {
    const float* p = xl + (size_t)s * D + coff;
    if constexpr (CPL == 8) {
      *(float4*)&r[0] = *(const float4*)p;
      *(float4*)&r[4] = *(const float4*)(p + 4);
    } else {
      *(float2*)&r[0] = *(const float2*)p;
    }
  };
  auto score = [&](const float* r) {
    float p = 0.f;
#pragma unroll
    for (int j = 0; j < CPL; ++j) {
      float t = r[j] + xrv[j];
      t = t >= 0.f ? t : 0.2f * t;
      p = fmaf(t, attv[j], p);
    }
    return p;
  };

  float m = -INFINITY, den = 0.f;
  int i = off[node];
  const int iend = off[node + 1];
  for (; i + 4 <= iend; i += 4) {
    const int s0 = csrc[i], s1 = csrc[i + 1];
    const int s2 = csrc[i + 2], s3 = csrc[i + 3];
    float r0[CPL], r1[CPL], r2[CPL], r3[CPL];
    loadrow(s0, r0);
    loadrow(s1, r1);
    loadrow(s2, r2);
    loadrow(s3, r3);
    float p0 = score(r0), p1 = score(r1), p2 = score(r2), p3 = score(r3);
#pragma unroll
    for (int msk = 1; msk < 16; msk <<= 1) {
      p0 += __shfl_xor(p0, msk);
      p1 += __shfl_xor(p1, msk);
      p2 += __shfl_xor(p2, msk);
      p3 += __shfl_xor(p3, msk);
    }
    const float nm = fmaxf(fmaxf(m, fmaxf(p0, p1)), fmaxf(p2, p3));
    const float sc = __expf(m - nm);  // 0 when m == -inf
    const float w0 = __expf(p0 - nm), w1 = __expf(p1 - nm);
    const float w2 = __expf(p2 - nm), w3 = __expf(p3 - nm);
    den = fmaf(den, sc, (w0 + w1) + (w2 + w3));
#pragma unroll
    for (int j = 0; j < CPL; ++j) {
      const float t = fmaf(w0, r0[j], fmaf(w1, r1[j], fmaf(w2, r2[j], w3 * r3[j])));
      acc[j] = fmaf(acc[j], sc, t);
    }
    m = nm;
  }
  for (; i < iend; ++i) {
    const int s0 = csrc[i];
    float r0[CPL];
    loadrow(s0, r0);
    float p0 = score(r0);
#pragma unroll
    for (int msk = 1; msk < 16; msk <<= 1) p0 += __shfl_xor(p0, msk);
    const float nm = fmaxf(m, p0);
    const float sc = __expf(m - nm);
    const float w0 = __expf(p0 - nm);
    den = fmaf(den, sc, w0);
#pragma unroll
    for (int j = 0; j < CPL; ++j) acc[j] = fmaf(acc[j], sc, w0 * r0[j]);
    m = nm;
  }

  const float inv = (den > 0.f) ? 1.f / den : 0.f;
  unsigned short hi[CPL], lo[CPL];
#pragma unroll
  for (int j = 0; j < CPL; ++j) {
    float o = fmaf(acc[j], inv, bias[coff + j]);
    o = o > 0.f ? o : 0.f;  // relu (layer output)
    hi[j] = f2bf(o);
    lo[j] = f2bf(o - bf2f(hi[j]));
  }
  unsigned short* po = outcat + (size_t)node * (2 * D) + coff;
  if constexpr (CPL == 8) {
    *(ushort8*)po = *(ushort8*)hi;
    *(ushort8*)(po + D) = *(ushort8*)lo;
  } else {
    *(ushort2v*)po = *(ushort2v*)hi;
    *(ushort2v*)(po + D) = *(ushort2v*)lo;
  }
}

// ============ launch ============
extern "C" void kernel_launch(void* const* d_in, const int* in_sizes, int n_in,
                              void* d_out, int out_size, void* d_ws,
                              size_t ws_size, hipStream_t stream) {
  const float* x    = (const float*)d_in[0];
  const int*   ei   = (const int*)d_in[1];
  const float* Wl1  = (const float*)d_in[3];
  const float* bl1  = (const float*)d_in[4];
  const float* Wr1  = (const float*)d_in[5];
  const float* br1  = (const float*)d_in[6];
  const float* att1 = (const float*)d_in[7];
  const float* bias1= (const float*)d_in[8];
  const float* Wl2  = (const float*)d_in[9];
  const float* bl2  = (const float*)d_in[10];
  const float* Wr2  = (const float*)d_in[11];
  const float* br2  = (const float*)d_in[12];
  const float* att2 = (const float*)d_in[13];
  const float* bias2= (const float*)d_in[14];
  const float* Wlin = (const float*)d_in[15];
  const float* blin = (const float*)d_in[16];
  float* out = (float*)d_out;

  const int N = in_sizes[0] / 128;  // 20000
  const int E = in_sizes[1] / 2;    // 160000
  const int* srcA = ei;
  const int* dstA = ei + E;

  // -------- workspace layout (~93.8 MB, unchanged from passing round) -----
  char* base = (char*)d_ws;
  float* xl2 = (float*)base;                        // 40,960,000 B
  float* xr2 = (float*)(base + 40960000);           // 40,960,000 B
  unsigned short* h1cat = (unsigned short*)(base + 81920000);  // 10,240,000 B
  unsigned short* wb = (unsigned short*)(base + 92160000);     // 786,432 B
  unsigned short* wl1t = wb;               // 128x256
  unsigned short* wr1t = wb + 32768;
  unsigned short* wl2t = wb + 65536;       // 512x256
  unsigned short* wr2t = wb + 196608;
  unsigned short* wlint = wb + 327680;     // 64x1024
  int* ib = (int*)(base + 92946432);
  int* deg = ib;
  int* off = ib + 20000;
  int* cursor = ib + 40001;
  int* csrc = ib + 60001;
  // aliases inside xl2 region (dead before xl2 is written):
  unsigned short* xcat = (unsigned short*)xl2;          // 10,240,000 B
  float* xl1 = (float*)(base + 10240000);               // 10,240,000 B
  float* xr1 = (float*)(base + 20480000);               // 10,240,000 B
  unsigned short* h2cat = (unsigned short*)xr2;         // in-place over xr2

  // -------- CSR build --------
  hipMemsetAsync(deg, 0, (size_t)N * sizeof(int), stream);
  count_deg<<<dim3((E + 255) / 256), dim3(256), 0, stream>>>(dstA, deg, E);
  scan_offsets<<<dim3(1), dim3(1024), 0, stream>>>(deg, off, cursor, N);
  scatter_edges<<<dim3((E + 255) / 256), dim3(256), 0, stream>>>(
      srcA, dstA, cursor, csrc, E);

  // -------- casts --------
  split_x_k<<<dim3((N * 128 + 255) / 256), dim3(256), 0, stream>>>(
      x, xcat, N * 128);
  wsplit_t_k<<<dim3(1, 128), dim3(256), 0, stream>>>(Wl1, wl1t, 128, 128);
  wsplit_t_k<<<dim3(1, 128), dim3(256), 0, stream>>>(Wr1, wr1t, 128, 128);
  wsplit_t_k<<<dim3(2, 128), dim3(256), 0, stream>>>(Wl2, wl2t, 128, 512);
  wsplit_t_k<<<dim3(2, 128), dim3(256), 0, stream>>>(Wr2, wr2t, 128, 512);
  wsplit_t_k<<<dim3(1, 512), dim3(256), 0, stream>>>(Wlin, wlint, 512, 64);

  const int gm = (N + 127) / 128;  // 157
  // -------- layer 1 (paired xl/xr GEMM) --------
  gemm_split<true><<<dim3(gm, 2), dim3(256), 0, stream>>>(
      xcat, 256, wl1t, wr1t, 256, bl1, br1, xl1, xr1, N, 128, 128);
  agg_fused<2><<<dim3((N + 3) / 4), dim3(256), 0, stream>>>(
      xl1, xr1, att1, bias1, off, csrc, h1cat, N);
  // -------- layer 2 (paired xl/xr GEMM) --------
  gemm_split<true><<<dim3(gm, 8), dim3(256), 0, stream>>>(
      h1cat, 256, wl2t, wr2t, 256, bl2, br2, xl2, xr2, N, 512, 128);
  agg_fused<8><<<dim3((N + 3) / 4), dim3(256), 0, stream>>>(
      xl2, xr2, att2, bias2, off, csrc, h2cat, N);
  // -------- output linear --------
  gemm_split<false><<<dim3(gm, 1), dim3(256), 0, stream>>>(
      h2cat, 1024, wlint, nullptr, 1024, blin, nullptr, out, nullptr,
      N, 64, 512);
}